// Round 6
// baseline (230.019 us; speedup 1.0000x reference)
//
#include <hip/hip_runtime.h>
#include <hip/hip_bf16.h>
#include <math.h>

#define N_NODES 50000
#define N_EDGES 800000
#define IN_DIM  128
#define OUT_DIM 64
#define LEAKY   0.01f

#define PROJ_ROWS 64
#define PROJ_NB   ((N_NODES + PROJ_ROWS - 1) / PROJ_ROWS)   // 782

#define SCAN_B   1024
#define SCAN_NB  ((N_NODES + SCAN_B - 1) / SCAN_B)          // 49

// ---------------------------------------------------------------------------
// z = feat @ W (stored bf16), az epilogue. 256 threads, 64 rows/block,
// feat tile in LDS. Wave w computes rows [w*16, w*16+16), lane = output col.
__global__ __launch_bounds__(256) void proj_kernel(
        const float* __restrict__ feat, const float* __restrict__ W,
        const float* __restrict__ a,
        __hip_bfloat16* __restrict__ zb,
        float* __restrict__ az_src, float* __restrict__ az_dst) {
    __shared__ float fs[PROJ_ROWS * IN_DIM];                // 32 KB
    int tid  = threadIdx.x;
    int row0 = blockIdx.x * PROJ_ROWS;
    int nrows = N_NODES - row0; if (nrows > PROJ_ROWS) nrows = PROJ_ROWS;

    const float4* gsrc = (const float4*)(feat + (size_t)row0 * IN_DIM);
    if (nrows == PROJ_ROWS) {
#pragma unroll
        for (int i = 0; i < 8; ++i) {
            int idx = tid + i * 256;
            ((float4*)fs)[idx] = gsrc[idx];
        }
    } else {
        int lim = nrows * (IN_DIM / 4);
#pragma unroll
        for (int i = 0; i < 8; ++i) {
            int idx = tid + i * 256;
            if (idx < lim) ((float4*)fs)[idx] = gsrc[idx];
        }
    }
    __syncthreads();

    int lane  = tid & 63;
    int rbase = (tid >> 6) * 16;

    float acc[16];
#pragma unroll
    for (int r = 0; r < 16; ++r) acc[r] = 0.f;

    for (int kk = 0; kk < IN_DIM / 4; ++kk) {
        float w0 = W[(kk * 4 + 0) * OUT_DIM + lane];
        float w1 = W[(kk * 4 + 1) * OUT_DIM + lane];
        float w2 = W[(kk * 4 + 2) * OUT_DIM + lane];
        float w3 = W[(kk * 4 + 3) * OUT_DIM + lane];
#pragma unroll
        for (int r = 0; r < 16; ++r) {
            float4 f = *(const float4*)&fs[(rbase + r) * IN_DIM + kk * 4];
            acc[r] = fmaf(f.x, w0, acc[r]);
            acc[r] = fmaf(f.y, w1, acc[r]);
            acc[r] = fmaf(f.z, w2, acc[r]);
            acc[r] = fmaf(f.w, w3, acc[r]);
        }
    }

    float a1 = a[lane], a2 = a[OUT_DIM + lane];
#pragma unroll
    for (int r = 0; r < 16; ++r) {
        int row = row0 + rbase + r;
        if (row < N_NODES) {
            zb[(size_t)row * OUT_DIM + lane] = __float2bfloat16(acc[r]);
            float s1 = acc[r] * a1;
            float s2 = acc[r] * a2;
#pragma unroll
            for (int off = 32; off > 0; off >>= 1) {
                s1 += __shfl_xor(s1, off, 64);
                s2 += __shfl_xor(s2, off, 64);
            }
            if (lane == r) { az_src[row] = s1; az_dst[row] = s2; }
        }
    }
}

// ---------------------------------------------------------------------------
// degree histogram (no rank write)
__global__ __launch_bounds__(256) void hist_kernel(
        const int* __restrict__ dst, int* __restrict__ counts) {
    int i = blockIdx.x * 256 + threadIdx.x;
    if (i < N_EDGES) atomicAdd(&counts[dst[i]], 1);
}

// ---------------------------------------------------------------------------
// scan step 1: per-block exclusive scan, block totals out
__global__ __launch_bounds__(SCAN_B) void scan1_kernel(
        const int* __restrict__ counts, int* __restrict__ offsets,
        int* __restrict__ blocksums) {
    __shared__ int s[SCAN_B];
    int i = blockIdx.x * SCAN_B + threadIdx.x;
    int v = (i < N_NODES) ? counts[i] : 0;
    s[threadIdx.x] = v;
    __syncthreads();
    for (int off = 1; off < SCAN_B; off <<= 1) {
        int t = (threadIdx.x >= off) ? s[threadIdx.x - off] : 0;
        __syncthreads();
        s[threadIdx.x] += t;
        __syncthreads();
    }
    if (i < N_NODES) offsets[i] = s[threadIdx.x] - v;
    if (threadIdx.x == SCAN_B - 1) blocksums[blockIdx.x] = s[SCAN_B - 1];
}

// scan step 2+3 fused: every block wave-scans the 49 block sums itself,
// adds its block offset, inits cursor, seals offsets[N]
__global__ __launch_bounds__(SCAN_B) void scan3_kernel(
        int* __restrict__ offsets, int* __restrict__ cursor,
        const int* __restrict__ blocksums) {
    __shared__ int bs[64];
    if (threadIdx.x < 64) {
        int lane = threadIdx.x;
        int v = (lane < SCAN_NB) ? blocksums[lane] : 0;
        int inc = v;
#pragma unroll
        for (int off = 1; off < 64; off <<= 1) {
            int t = __shfl_up(inc, off, 64);
            if (lane >= off) inc += t;
        }
        bs[lane] = inc - v;
    }
    __syncthreads();
    int i = blockIdx.x * SCAN_B + threadIdx.x;
    if (i < N_NODES) {
        int o = offsets[i] + bs[blockIdx.x];
        offsets[i] = o;
        cursor[i]  = o;
    }
    if (i == 0) offsets[N_NODES] = N_EDGES;
}

// ---------------------------------------------------------------------------
// CSR build: slot from atomic cursor (L2-hot 200KB), ONE 4B scatter per edge
// into a 3.2MB buffer (L2-resident -> no write amplification).
__global__ __launch_bounds__(256) void build_csr_kernel(
        const int* __restrict__ src, const int* __restrict__ dst,
        int* __restrict__ cursor, int* __restrict__ src_sorted) {
    int i = blockIdx.x * 256 + threadIdx.x;
    if (i >= N_EDGES) return;
    int pos = atomicAdd(&cursor[dst[i]], 1);
    src_sorted[pos] = src[i];
}

// ---------------------------------------------------------------------------
// single-pass softmax-aggregation. One wave per node, lane = dim.
// Edge metadata (src idx + az_src value) is loaded LANE-PARALLEL in 64-edge
// chunks (1 coalesced load + 1 gather instruction for 64 edges), then
// broadcast per-edge via __shfl with wave-uniform (readfirstlane'd) bounds.
// Only remaining per-edge VMEM op is the 128B bf16 z-row gather.
__global__ __launch_bounds__(256) void node_fused_kernel(
        const int* __restrict__ offsets, const int* __restrict__ src_sorted,
        const float* __restrict__ az_src, const float* __restrict__ az_dst,
        const __hip_bfloat16* __restrict__ zb, float* __restrict__ h) {
    int lane = threadIdx.x & 63;
    int w    = threadIdx.x >> 6;
    int t    = blockIdx.x * 4 + w;
    if (t >= N_NODES) return;
    int beg = __builtin_amdgcn_readfirstlane(offsets[t]);
    int end = __builtin_amdgcn_readfirstlane(offsets[t + 1]);
    float az_d = az_dst[t];

    float acc0 = 0.f, acc1 = 0.f, acc2 = 0.f, acc3 = 0.f;
    float ss0 = 0.f, ss1 = 0.f, ss2 = 0.f, ss3 = 0.f;

    for (int chunk = beg; chunk < end; chunk += 64) {
        int m = end - chunk; if (m > 64) m = 64;
        // lane-parallel: 64 edge srcs + their az values in 2 instructions
        int   si = 0;
        float av = 0.f;
        if (lane < m) {
            si = src_sorted[chunk + lane];   // coalesced 256B
            av = az_src[si];                 // lane-parallel gather (L2-hot)
        }
        int j = 0;
        for (; j + 4 <= m; j += 4) {
            int s0 = __shfl(si, j,     64);
            int s1 = __shfl(si, j + 1, 64);
            int s2 = __shfl(si, j + 2, 64);
            int s3 = __shfl(si, j + 3, 64);
            float v0 = __shfl(av, j,     64) + az_d;
            float v1 = __shfl(av, j + 1, 64) + az_d;
            float v2 = __shfl(av, j + 2, 64) + az_d;
            float v3 = __shfl(av, j + 3, 64) + az_d;
            v0 = v0 > 0.f ? v0 : LEAKY * v0;
            v1 = v1 > 0.f ? v1 : LEAKY * v1;
            v2 = v2 > 0.f ? v2 : LEAKY * v2;
            v3 = v3 > 0.f ? v3 : LEAKY * v3;
            float x0 = __expf(v0), x1 = __expf(v1);
            float x2 = __expf(v2), x3 = __expf(v3);
            ss0 += x0; ss1 += x1; ss2 += x2; ss3 += x3;
            acc0 = fmaf(x0, __bfloat162float(zb[(size_t)s0 * OUT_DIM + lane]), acc0);
            acc1 = fmaf(x1, __bfloat162float(zb[(size_t)s1 * OUT_DIM + lane]), acc1);
            acc2 = fmaf(x2, __bfloat162float(zb[(size_t)s2 * OUT_DIM + lane]), acc2);
            acc3 = fmaf(x3, __bfloat162float(zb[(size_t)s3 * OUT_DIM + lane]), acc3);
        }
        for (; j < m; ++j) {
            int   s0 = __shfl(si, j, 64);
            float v0 = __shfl(av, j, 64) + az_d;
            v0 = v0 > 0.f ? v0 : LEAKY * v0;
            float x0 = __expf(v0);
            ss0 += x0;
            acc0 = fmaf(x0, __bfloat162float(zb[(size_t)s0 * OUT_DIM + lane]), acc0);
        }
    }
    float ssum = (ss0 + ss1) + (ss2 + ss3);
    float inv  = (end > beg) ? 1.f / ssum : 0.f;
    h[(size_t)t * OUT_DIM + lane] = ((acc0 + acc1) + (acc2 + acc3)) * inv;
}

// ---------------------------------------------------------------------------
extern "C" void kernel_launch(void* const* d_in, const int* in_sizes, int n_in,
                              void* d_out, int out_size, void* d_ws, size_t ws_size,
                              hipStream_t stream) {
    const float* feat = (const float*)d_in[0];
    const int*   src  = (const int*)  d_in[1];
    const int*   dst  = (const int*)  d_in[2];
    const float* W    = (const float*)d_in[3];
    const float* a    = (const float*)d_in[4];
    float* h = (float*)d_out;

    // workspace layout
    float* az_src     = (float*)d_ws;                        // N
    float* az_dst     = az_src + N_NODES;                    // N
    int*   counts     = (int*)(az_dst + N_NODES);            // N
    int*   offsets    = counts + N_NODES;                    // N+1
    int*   cursor     = offsets + N_NODES + 1;               // N
    int*   blocksums  = cursor + N_NODES;                    // 64
    int*   src_sorted = blocksums + 64;                      // E
    __hip_bfloat16* zb = (__hip_bfloat16*)(src_sorted + N_EDGES); // N*64

    hipMemsetAsync(counts, 0, sizeof(int) * N_NODES, stream);

    int eblocks = (N_EDGES + 255) / 256;
    hist_kernel<<<eblocks, 256, 0, stream>>>(dst, counts);
    scan1_kernel<<<SCAN_NB, SCAN_B, 0, stream>>>(counts, offsets, blocksums);
    scan3_kernel<<<SCAN_NB, SCAN_B, 0, stream>>>(offsets, cursor, blocksums);

    proj_kernel<<<PROJ_NB, 256, 0, stream>>>(feat, W, a, zb, az_src, az_dst);

    build_csr_kernel<<<eblocks, 256, 0, stream>>>(src, dst, cursor, src_sorted);

    node_fused_kernel<<<(N_NODES + 3) / 4, 256, 0, stream>>>(
        offsets, src_sorted, az_src, az_dst, zb, h);
}

// Round 7
// 193.062 us; speedup vs baseline: 1.1914x; 1.1914x over previous
//
#include <hip/hip_runtime.h>
#include <hip/hip_bf16.h>
#include <math.h>

#define N_NODES 50000
#define N_EDGES 800000
#define IN_DIM  128
#define OUT_DIM 64
#define LEAKY   0.01f

#define PROJ_ROWS 64
#define PROJ_NB   ((N_NODES + PROJ_ROWS - 1) / PROJ_ROWS)   // 782
#define HIST_NB   ((N_EDGES + 255) / 256)                   // 3125

#define SCAN_B   1024
#define SCAN_NB  ((N_NODES + SCAN_B - 1) / SCAN_B)          // 49

// ---------------------------------------------------------------------------
// FUSED: blocks [0, PROJ_NB) do z = feat @ W (+az epilogue);
//        blocks [PROJ_NB, PROJ_NB+HIST_NB) do degree histogram + rank.
// The two jobs touch disjoint data and run concurrently in one launch.
__global__ __launch_bounds__(256) void proj_hist_kernel(
        const float* __restrict__ feat, const float* __restrict__ W,
        const float* __restrict__ a,
        __hip_bfloat16* __restrict__ zb,
        float* __restrict__ az_src, float* __restrict__ az_dst,
        const int* __restrict__ dst, int* __restrict__ counts,
        int* __restrict__ rank) {
    __shared__ float fs[PROJ_ROWS * IN_DIM];                // 32 KB
    int tid = threadIdx.x;

    if (blockIdx.x >= PROJ_NB) {
        // ---- histogram part: one edge per thread, coalesced rank write ----
        int i = (blockIdx.x - PROJ_NB) * 256 + tid;
        if (i < N_EDGES) rank[i] = atomicAdd(&counts[dst[i]], 1);
        return;
    }

    // ---- projection part ----
    int row0 = blockIdx.x * PROJ_ROWS;
    int nrows = N_NODES - row0; if (nrows > PROJ_ROWS) nrows = PROJ_ROWS;

    const float4* gsrc = (const float4*)(feat + (size_t)row0 * IN_DIM);
    if (nrows == PROJ_ROWS) {
#pragma unroll
        for (int i = 0; i < 8; ++i) {
            int idx = tid + i * 256;
            ((float4*)fs)[idx] = gsrc[idx];
        }
    } else {
        int lim = nrows * (IN_DIM / 4);
#pragma unroll
        for (int i = 0; i < 8; ++i) {
            int idx = tid + i * 256;
            if (idx < lim) ((float4*)fs)[idx] = gsrc[idx];
        }
    }
    __syncthreads();

    int lane  = tid & 63;
    int rbase = (tid >> 6) * 16;

    float acc[16];
#pragma unroll
    for (int r = 0; r < 16; ++r) acc[r] = 0.f;

    for (int kk = 0; kk < IN_DIM / 4; ++kk) {
        float w0 = W[(kk * 4 + 0) * OUT_DIM + lane];
        float w1 = W[(kk * 4 + 1) * OUT_DIM + lane];
        float w2 = W[(kk * 4 + 2) * OUT_DIM + lane];
        float w3 = W[(kk * 4 + 3) * OUT_DIM + lane];
#pragma unroll
        for (int r = 0; r < 16; ++r) {
            float4 f = *(const float4*)&fs[(rbase + r) * IN_DIM + kk * 4];
            acc[r] = fmaf(f.x, w0, acc[r]);
            acc[r] = fmaf(f.y, w1, acc[r]);
            acc[r] = fmaf(f.z, w2, acc[r]);
            acc[r] = fmaf(f.w, w3, acc[r]);
        }
    }

    float a1 = a[lane], a2 = a[OUT_DIM + lane];
#pragma unroll
    for (int r = 0; r < 16; ++r) {
        int row = row0 + rbase + r;
        if (row < N_NODES) {
            zb[(size_t)row * OUT_DIM + lane] = __float2bfloat16(acc[r]);
            float s1 = acc[r] * a1;
            float s2 = acc[r] * a2;
#pragma unroll
            for (int off = 32; off > 0; off >>= 1) {
                s1 += __shfl_xor(s1, off, 64);
                s2 += __shfl_xor(s2, off, 64);
            }
            if (lane == r) { az_src[row] = s1; az_dst[row] = s2; }
        }
    }
}

// ---------------------------------------------------------------------------
// scan step 1: per-block exclusive scan, block totals out
__global__ __launch_bounds__(SCAN_B) void scan1_kernel(
        const int* __restrict__ counts, int* __restrict__ offsets,
        int* __restrict__ blocksums) {
    __shared__ int s[SCAN_B];
    int i = blockIdx.x * SCAN_B + threadIdx.x;
    int v = (i < N_NODES) ? counts[i] : 0;
    s[threadIdx.x] = v;
    __syncthreads();
    for (int off = 1; off < SCAN_B; off <<= 1) {
        int t = (threadIdx.x >= off) ? s[threadIdx.x - off] : 0;
        __syncthreads();
        s[threadIdx.x] += t;
        __syncthreads();
    }
    if (i < N_NODES) offsets[i] = s[threadIdx.x] - v;
    if (threadIdx.x == SCAN_B - 1) blocksums[blockIdx.x] = s[SCAN_B - 1];
}

// scan step 2+3 fused: every block wave-scans the 49 block sums itself,
// then adds its block offset; seal offsets[N]
__global__ __launch_bounds__(SCAN_B) void scan3_kernel(
        int* __restrict__ offsets, const int* __restrict__ blocksums) {
    __shared__ int bs[64];
    if (threadIdx.x < 64) {
        int lane = threadIdx.x;
        int v = (lane < SCAN_NB) ? blocksums[lane] : 0;
        int inc = v;
#pragma unroll
        for (int off = 1; off < 64; off <<= 1) {
            int t = __shfl_up(inc, off, 64);
            if (lane >= off) inc += t;
        }
        bs[lane] = inc - v;
    }
    __syncthreads();
    int i = blockIdx.x * SCAN_B + threadIdx.x;
    if (i < N_NODES) offsets[i] += bs[blockIdx.x];
    if (i == 0) offsets[N_NODES] = N_EDGES;
}

// ---------------------------------------------------------------------------
// CSR build, atomic-free: pos = offsets[dst] + rank. ONE 4B NON-TEMPORAL
// scatter per edge -- bypasses L2 so random 4B writes don't each evict a
// full dirty 64B line (R6 counters: 52.8MB write-back for a 3.2MB payload).
__global__ __launch_bounds__(256) void build_csr_kernel(
        const int* __restrict__ src, const int* __restrict__ dst,
        const int* __restrict__ rank, const int* __restrict__ offsets,
        int* __restrict__ src_sorted) {
    int i = blockIdx.x * 256 + threadIdx.x;
    if (i >= N_EDGES) return;
    int t = dst[i];
    int pos = offsets[t] + rank[i];    // offsets L2-hot (200KB)
    __builtin_nontemporal_store(src[i], &src_sorted[pos]);
}

// ---------------------------------------------------------------------------
// single-pass softmax-aggregation. One wave per node, lane = dim.
// e recomputed from az (L2-hot); ssum lane-redundant (no reduction needed).
__global__ __launch_bounds__(256) void node_fused_kernel(
        const int* __restrict__ offsets, const int* __restrict__ src_sorted,
        const float* __restrict__ az_src, const float* __restrict__ az_dst,
        const __hip_bfloat16* __restrict__ zb, float* __restrict__ h) {
    int lane = threadIdx.x & 63;
    int w    = threadIdx.x >> 6;
    int t    = blockIdx.x * 4 + w;
    if (t >= N_NODES) return;
    int beg = offsets[t];
    int end = offsets[t + 1];
    float az_d = az_dst[t];

    float acc0 = 0.f, acc1 = 0.f, acc2 = 0.f, acc3 = 0.f;
    float ss0 = 0.f, ss1 = 0.f, ss2 = 0.f, ss3 = 0.f;
    int i = beg;
    for (; i + 4 <= end; i += 4) {
        int s0 = src_sorted[i];
        int s1 = src_sorted[i + 1];
        int s2 = src_sorted[i + 2];
        int s3 = src_sorted[i + 3];
        float v0 = az_src[s0] + az_d;
        float v1 = az_src[s1] + az_d;
        float v2 = az_src[s2] + az_d;
        float v3 = az_src[s3] + az_d;
        v0 = v0 > 0.f ? v0 : LEAKY * v0;
        v1 = v1 > 0.f ? v1 : LEAKY * v1;
        v2 = v2 > 0.f ? v2 : LEAKY * v2;
        v3 = v3 > 0.f ? v3 : LEAKY * v3;
        float x0 = __expf(v0), x1 = __expf(v1);
        float x2 = __expf(v2), x3 = __expf(v3);
        ss0 += x0; ss1 += x1; ss2 += x2; ss3 += x3;
        acc0 = fmaf(x0, __bfloat162float(zb[(size_t)s0 * OUT_DIM + lane]), acc0);
        acc1 = fmaf(x1, __bfloat162float(zb[(size_t)s1 * OUT_DIM + lane]), acc1);
        acc2 = fmaf(x2, __bfloat162float(zb[(size_t)s2 * OUT_DIM + lane]), acc2);
        acc3 = fmaf(x3, __bfloat162float(zb[(size_t)s3 * OUT_DIM + lane]), acc3);
    }
    for (; i < end; ++i) {
        int s0 = src_sorted[i];
        float v0 = az_src[s0] + az_d;
        v0 = v0 > 0.f ? v0 : LEAKY * v0;
        float x0 = __expf(v0);
        ss0 += x0;
        acc0 = fmaf(x0, __bfloat162float(zb[(size_t)s0 * OUT_DIM + lane]), acc0);
    }
    float ssum = (ss0 + ss1) + (ss2 + ss3);
    float inv  = (end > beg) ? 1.f / ssum : 0.f;
    h[(size_t)t * OUT_DIM + lane] = ((acc0 + acc1) + (acc2 + acc3)) * inv;
}

// ---------------------------------------------------------------------------
extern "C" void kernel_launch(void* const* d_in, const int* in_sizes, int n_in,
                              void* d_out, int out_size, void* d_ws, size_t ws_size,
                              hipStream_t stream) {
    const float* feat = (const float*)d_in[0];
    const int*   src  = (const int*)  d_in[1];
    const int*   dst  = (const int*)  d_in[2];
    const float* W    = (const float*)d_in[3];
    const float* a    = (const float*)d_in[4];
    float* h = (float*)d_out;

    // workspace layout
    float* az_src     = (float*)d_ws;                        // N
    float* az_dst     = az_src + N_NODES;                    // N
    int*   counts     = (int*)(az_dst + N_NODES);            // N
    int*   offsets    = counts + N_NODES;                    // N+1
    int*   blocksums  = offsets + N_NODES + 1;               // 64
    int*   rank       = blocksums + 64;                      // E
    int*   src_sorted = rank + N_EDGES;                      // E
    __hip_bfloat16* zb = (__hip_bfloat16*)(src_sorted + N_EDGES); // N*64

    hipMemsetAsync(counts, 0, sizeof(int) * N_NODES, stream);

    proj_hist_kernel<<<PROJ_NB + HIST_NB, 256, 0, stream>>>(
        feat, W, a, zb, az_src, az_dst, dst, counts, rank);

    scan1_kernel<<<SCAN_NB, SCAN_B, 0, stream>>>(counts, offsets, blocksums);
    scan3_kernel<<<SCAN_NB, SCAN_B, 0, stream>>>(offsets, blocksums);

    build_csr_kernel<<<HIST_NB, 256, 0, stream>>>(src, dst, rank, offsets,
                                                  src_sorted);

    node_fused_kernel<<<(N_NODES + 3) / 4, 256, 0, stream>>>(
        offsets, src_sorted, az_src, az_dst, zb, h);
}